// Round 1
// baseline (1557.946 us; speedup 1.0000x reference)
//
#include <hip/hip_runtime.h>

#define HD 128
#define BN_EPS 1e-5f

// ---------------- degree / normalization ----------------

__global__ __launch_bounds__(256) void k_deg(const int* __restrict__ dst, float* __restrict__ deg, int E) {
    int e = blockIdx.x * 256 + threadIdx.x;
    if (e < E) unsafeAtomicAdd(&deg[dst[e]], 1.0f);
}

__global__ __launch_bounds__(256) void k_dinv(float* __restrict__ deg, int N) {
    int n = blockIdx.x * 256 + threadIdx.x;
    if (n < N) deg[n] = rsqrtf(deg[n] + 1.0f);
}

__global__ __launch_bounds__(256) void k_ew(const int* __restrict__ src, const int* __restrict__ dst,
                                            const float* __restrict__ dinv, float* __restrict__ ew, int E) {
    int e = blockIdx.x * 256 + threadIdx.x;
    if (e < E) ew[e] = dinv[src[e]] * dinv[dst[e]];
}

// ---------------- GEMM: C[N,128] = A[N,128] @ W[128,128] ----------------
// 32 rows/block, 256 threads, thread computes 4 rows x 4 cols.
// LDS: W 64KB + A-tile 16KB = 80KB -> 2 blocks/CU.

__global__ __launch_bounds__(256) void k_gemm(const float* __restrict__ A, const float* __restrict__ W,
                                              float* __restrict__ C, int N) {
    __shared__ float As[32][HD];
    __shared__ float Ws[HD][HD];
    const int t = threadIdx.x;
    const int row0 = blockIdx.x * 32;

    for (int i = t; i < HD * HD / 4; i += 256)
        ((float4*)Ws)[i] = ((const float4*)W)[i];
    for (int i = t; i < 32 * HD / 4; i += 256) {
        int r = i >> 5;
        int gr = row0 + r;
        float4 v = make_float4(0.f, 0.f, 0.f, 0.f);
        if (gr < N) v = ((const float4*)A)[(size_t)gr * (HD / 4) + (i & 31)];
        ((float4*)As)[i] = v;
    }
    __syncthreads();

    const int tx = t & 31, ty = t >> 5;
    const int c0 = tx * 4, r0 = ty * 4;
    float acc[4][4] = {};
#pragma unroll 8
    for (int k = 0; k < HD; ++k) {
        const float4 w = *(const float4*)&Ws[k][c0];
#pragma unroll
        for (int i = 0; i < 4; ++i) {
            const float a = As[r0 + i][k];
            acc[i][0] = fmaf(a, w.x, acc[i][0]);
            acc[i][1] = fmaf(a, w.y, acc[i][1]);
            acc[i][2] = fmaf(a, w.z, acc[i][2]);
            acc[i][3] = fmaf(a, w.w, acc[i][3]);
        }
    }
#pragma unroll
    for (int i = 0; i < 4; ++i) {
        int gr = row0 + r0 + i;
        if (gr < N)
            *(float4*)&C[(size_t)gr * HD + c0] =
                make_float4(acc[i][0], acc[i][1], acc[i][2], acc[i][3]);
    }
}

// ---------------- aggregation ----------------

// agg[n][f] = hW[n][f] * dinv[n]^2 + b[f]
__global__ __launch_bounds__(256) void k_agg_init(const float* __restrict__ hW, const float* __restrict__ dinv,
                                                  const float* __restrict__ b, float* __restrict__ agg, int N) {
    int tid = blockIdx.x * 256 + threadIdx.x;  // over N*32 float4
    if (tid >= N * 32) return;
    int n = tid >> 5, q = tid & 31;
    float sw = dinv[n];
    sw *= sw;
    float4 v = ((const float4*)hW)[tid];
    const float4 bb = ((const float4*)b)[q];
    float4 o;
    o.x = fmaf(v.x, sw, bb.x);
    o.y = fmaf(v.y, sw, bb.y);
    o.z = fmaf(v.z, sw, bb.z);
    o.w = fmaf(v.w, sw, bb.w);
    ((float4*)agg)[tid] = o;
}

// one thread per (edge, feature): agg[dst] += h[src] * ew
__global__ __launch_bounds__(256) void k_scatter(const float* __restrict__ h, float* __restrict__ agg,
                                                 const int* __restrict__ src, const int* __restrict__ dst,
                                                 const float* __restrict__ ew, long long EH) {
    long long tid = (long long)blockIdx.x * 256 + threadIdx.x;
    if (tid >= EH) return;
    int e = (int)(tid >> 7), f = (int)(tid & 127);
    int s = src[e], d = dst[e];
    float w = ew[e];
    unsafeAtomicAdd(&agg[(size_t)d * HD + f], h[(size_t)s * HD + f] * w);
}

// ---------------- BatchNorm (training-mode batch stats) ----------------

__global__ __launch_bounds__(256) void k_bn_stats(const float* __restrict__ h, float* __restrict__ stats, int N) {
    const int f = threadIdx.x & 127;
    const int half = threadIdx.x >> 7;
    const int stride = gridDim.x * 2;
    float s = 0.f, sq = 0.f;
    for (int r = blockIdx.x * 2 + half; r < N; r += stride) {
        float v = h[(size_t)r * HD + f];
        s += v;
        sq = fmaf(v, v, sq);
    }
    unsafeAtomicAdd(&stats[f], s);
    unsafeAtomicAdd(&stats[HD + f], sq);
}

__global__ __launch_bounds__(128) void k_bn_fin(const float* __restrict__ stats, const float* __restrict__ g,
                                                const float* __restrict__ be, float* __restrict__ scsh,
                                                float invN) {
    int f = threadIdx.x;  // 128 threads
    float mean = stats[f] * invN;
    float var = fmaf(-mean, mean, stats[HD + f] * invN);
    float sc = g[f] * rsqrtf(var + BN_EPS);
    scsh[f] = sc;
    scsh[HD + f] = fmaf(-mean, sc, be[f]);
}

__global__ __launch_bounds__(256) void k_bn_apply(float* __restrict__ h, const float* __restrict__ scsh,
                                                  int N, int relu) {
    int tid = blockIdx.x * 256 + threadIdx.x;  // over N*32 float4
    if (tid >= N * 32) return;
    int q = tid & 31;
    float4 v = ((float4*)h)[tid];
    const float4 sc = ((const float4*)scsh)[q];
    const float4 sh = ((const float4*)(scsh + HD))[q];
    float4 o;
    o.x = fmaf(v.x, sc.x, sh.x);
    o.y = fmaf(v.y, sc.y, sh.y);
    o.z = fmaf(v.z, sc.z, sh.z);
    o.w = fmaf(v.w, sc.w, sh.w);
    if (relu) {
        o.x = fmaxf(o.x, 0.f);
        o.y = fmaxf(o.y, 0.f);
        o.z = fmaxf(o.z, 0.f);
        o.w = fmaxf(o.w, 0.f);
    }
    ((float4*)h)[tid] = o;
}

// ---------------- decode: out[q] = dot(h[u], h[v]) ----------------

__global__ __launch_bounds__(256) void k_decode(const float* __restrict__ h, const int* __restrict__ qu,
                                                const int* __restrict__ qv, float* __restrict__ out, int Q) {
    int tid = blockIdx.x * 256 + threadIdx.x;
    int wid = tid >> 6;
    int lane = threadIdx.x & 63;
    if (wid >= Q) return;
    int u = qu[wid], v = qv[wid];
    const float* ru = &h[(size_t)u * HD];
    const float* rv = &h[(size_t)v * HD];
    float p = ru[lane] * rv[lane] + ru[64 + lane] * rv[64 + lane];
#pragma unroll
    for (int off = 32; off; off >>= 1) p += __shfl_down(p, off);
    if (lane == 0) out[wid] = p;
}

// ---------------- launch ----------------

static inline size_t alignup(size_t x) { return (x + 511) & ~(size_t)511; }

extern "C" void kernel_launch(void* const* d_in, const int* in_sizes, int n_in,
                              void* d_out, int out_size, void* d_ws, size_t ws_size,
                              hipStream_t stream) {
    const float* x   = (const float*)d_in[0];
    const float* Wl[3] = {(const float*)d_in[1], (const float*)d_in[5], (const float*)d_in[9]};
    const float* bl[3] = {(const float*)d_in[2], (const float*)d_in[6], (const float*)d_in[10]};
    const float* gl[3] = {(const float*)d_in[3], (const float*)d_in[7], (const float*)d_in[11]};
    const float* bel[3] = {(const float*)d_in[4], (const float*)d_in[8], (const float*)d_in[12]};
    const int* ei  = (const int*)d_in[13];
    const int* eli = (const int*)d_in[14];

    const int N = in_sizes[0] / HD;
    const int E = in_sizes[13] / 2;
    const int Q = in_sizes[14] / 2;
    const int* src = ei;
    const int* dst = ei + E;
    const int* qu = eli;
    const int* qv = eli + Q;
    float* out = (float*)d_out;

    char* ws = (char*)d_ws;
    size_t off = 0;
    float* dinv  = (float*)(ws + off); off = alignup(off + (size_t)N * 4);
    float* ew    = (float*)(ws + off); off = alignup(off + (size_t)E * 4);
    float* stats = (float*)(ws + off); off = alignup(off + 512 * 4);
    float* hA    = (float*)(ws + off); off = alignup(off + (size_t)N * HD * 4);
    float* hB    = (float*)(ws + off); off = alignup(off + (size_t)N * HD * 4);
    (void)ws_size; (void)n_in; (void)out_size;

    const float invN = 1.0f / (float)N;
    const int nv = (N * 32 + 255) / 256;           // elementwise float4 grid
    const long long EH = (long long)E * HD;
    const int eg = (int)((EH + 255) / 256);

    // normalization coefficients
    hipMemsetAsync(dinv, 0, (size_t)N * 4, stream);
    k_deg<<<(E + 255) / 256, 256, 0, stream>>>(dst, dinv, E);
    k_dinv<<<(N + 255) / 256, 256, 0, stream>>>(dinv, N);
    k_ew<<<(E + 255) / 256, 256, 0, stream>>>(src, dst, dinv, ew, E);

    const float* hin = x;
    for (int l = 0; l < 3; ++l) {
        k_gemm<<<(N + 31) / 32, 256, 0, stream>>>(hin, Wl[l], hB, N);
        k_agg_init<<<nv, 256, 0, stream>>>(hB, dinv, bl[l], hA, N);
        k_scatter<<<eg, 256, 0, stream>>>(hB, hA, src, dst, ew, EH);
        hipMemsetAsync(stats, 0, 256 * 4, stream);
        k_bn_stats<<<512, 256, 0, stream>>>(hA, stats, N);
        k_bn_fin<<<1, HD, 0, stream>>>(stats, gl[l], bel[l], stats + 256, invN);
        k_bn_apply<<<nv, 256, 0, stream>>>(hA, stats + 256, N, (l < 2) ? 1 : 0);
        hin = hA;
    }

    k_decode<<<(Q + 3) / 4, 256, 0, stream>>>(hA, qu, qv, out, Q);
}

// Round 2
// 858.939 us; speedup vs baseline: 1.8138x; 1.8138x over previous
//
#include <hip/hip_runtime.h>

#define HD 128
#define BN_EPS 1e-5f

// ---------------- CSR build: count / dinv / scan / fill ----------------

__global__ __launch_bounds__(256) void k_count(const int* __restrict__ dst, int* __restrict__ cnt, int E) {
    int e = blockIdx.x * 256 + threadIdx.x;
    if (e < E) atomicAdd(&cnt[dst[e]], 1);
}

__global__ __launch_bounds__(256) void k_dinv(const int* __restrict__ cnt, float* __restrict__ dinv, int N) {
    int n = blockIdx.x * 256 + threadIdx.x;
    if (n < N) dinv[n] = rsqrtf((float)cnt[n] + 1.0f);
}

// block partial sums over 1024-element chunks
__global__ __launch_bounds__(256) void k_scan_a(const int* __restrict__ cnt, int* __restrict__ bsum, int N) {
    __shared__ int s[256];
    int base = blockIdx.x * 1024 + threadIdx.x * 4;
    int v = 0;
#pragma unroll
    for (int j = 0; j < 4; ++j) {
        int idx = base + j;
        if (idx < N) v += cnt[idx];
    }
    s[threadIdx.x] = v;
    __syncthreads();
    for (int o = 128; o; o >>= 1) {
        if (threadIdx.x < (unsigned)o) s[threadIdx.x] += s[threadIdx.x + o];
        __syncthreads();
    }
    if (threadIdx.x == 0) bsum[blockIdx.x] = s[0];
}

// serial exclusive scan of block sums (NB ~ 98, trivial)
__global__ void k_scan_b(int* __restrict__ bsum, int NB) {
    if (threadIdx.x == 0 && blockIdx.x == 0) {
        int acc = 0;
        for (int i = 0; i < NB; ++i) {
            int v = bsum[i];
            bsum[i] = acc;
            acc += v;
        }
    }
}

// per-chunk exclusive scan + block offset -> rowptr
__global__ __launch_bounds__(256) void k_scan_c(const int* __restrict__ cnt, const int* __restrict__ bsum,
                                                int* __restrict__ rowptr, int N) {
    __shared__ int s[256];
    const int t = threadIdx.x;
    int base = blockIdx.x * 1024 + t * 4;
    int v0 = 0, v1 = 0, v2 = 0, v3 = 0;
    if (base + 0 < N) v0 = cnt[base + 0];
    if (base + 1 < N) v1 = cnt[base + 1];
    if (base + 2 < N) v2 = cnt[base + 2];
    if (base + 3 < N) v3 = cnt[base + 3];
    int ts = v0 + v1 + v2 + v3;
    s[t] = ts;
    __syncthreads();
    for (int o = 1; o < 256; o <<= 1) {
        int add = (t >= o) ? s[t - o] : 0;
        __syncthreads();
        s[t] += add;
        __syncthreads();
    }
    int excl = s[t] - ts + bsum[blockIdx.x];
    if (base + 0 < N) rowptr[base + 0] = excl;
    if (base + 1 < N) rowptr[base + 1] = excl + v0;
    if (base + 2 < N) rowptr[base + 2] = excl + v0 + v1;
    if (base + 3 < N) rowptr[base + 3] = excl + v0 + v1 + v2;
}

// cursor starts as copy of rowptr; fill bumps it to row end
__global__ __launch_bounds__(256) void k_fill(const int* __restrict__ src, const int* __restrict__ dst,
                                              const float* __restrict__ dinv, int* __restrict__ cursor,
                                              int* __restrict__ csr_src, float* __restrict__ csr_w, int E) {
    int e = blockIdx.x * 256 + threadIdx.x;
    if (e >= E) return;
    int s = src[e], d = dst[e];
    int pos = atomicAdd(&cursor[d], 1);
    csr_src[pos] = s;
    csr_w[pos] = dinv[s] * dinv[d];
}

// ---------------- GEMM: C[N,128] = bn(A)[N,128] @ W[128,128] ----------------
// scsh != nullptr: apply per-feature scale/shift + ReLU to A on load (fused BN of prev layer).

__global__ __launch_bounds__(256) void k_gemm(const float* __restrict__ A, const float* __restrict__ W,
                                              float* __restrict__ C, int N, const float* __restrict__ scsh) {
    __shared__ float As[32][HD];
    __shared__ float Ws[HD][HD];
    const int t = threadIdx.x;
    const int row0 = blockIdx.x * 32;

    for (int i = t; i < HD * HD / 4; i += 256)
        ((float4*)Ws)[i] = ((const float4*)W)[i];
    for (int i = t; i < 32 * HD / 4; i += 256) {
        int r = i >> 5, q = i & 31;
        int gr = row0 + r;
        float4 v = make_float4(0.f, 0.f, 0.f, 0.f);
        if (gr < N) v = ((const float4*)A)[(size_t)gr * 32 + q];
        if (scsh) {
            const float4 sc = ((const float4*)scsh)[q];
            const float4 sh = ((const float4*)scsh)[32 + q];
            v.x = fmaxf(fmaf(v.x, sc.x, sh.x), 0.f);
            v.y = fmaxf(fmaf(v.y, sc.y, sh.y), 0.f);
            v.z = fmaxf(fmaf(v.z, sc.z, sh.z), 0.f);
            v.w = fmaxf(fmaf(v.w, sc.w, sh.w), 0.f);
        }
        ((float4*)As)[i] = v;
    }
    __syncthreads();

    const int tx = t & 31, ty = t >> 5;
    const int c0 = tx * 4, r0 = ty * 4;
    float acc[4][4] = {};
#pragma unroll 8
    for (int k = 0; k < HD; ++k) {
        const float4 w = *(const float4*)&Ws[k][c0];
#pragma unroll
        for (int i = 0; i < 4; ++i) {
            const float a = As[r0 + i][k];
            acc[i][0] = fmaf(a, w.x, acc[i][0]);
            acc[i][1] = fmaf(a, w.y, acc[i][1]);
            acc[i][2] = fmaf(a, w.z, acc[i][2]);
            acc[i][3] = fmaf(a, w.w, acc[i][3]);
        }
    }
#pragma unroll
    for (int i = 0; i < 4; ++i) {
        int gr = row0 + r0 + i;
        if (gr < N)
            *(float4*)&C[(size_t)gr * HD + c0] =
                make_float4(acc[i][0], acc[i][1], acc[i][2], acc[i][3]);
    }
}

// ---------------- fused aggregation: gather + self-loop + bias + BN stats ----------------
// one wave per node (grid-stride); lane holds features {2*lane, 2*lane+1}

#define GATHER_BLOCKS 1024

__global__ __launch_bounds__(256) void k_gather(const float* __restrict__ hW, const int* __restrict__ rowptr,
                                                const int* __restrict__ rowend, const int* __restrict__ csr_src,
                                                const float* __restrict__ csr_w, const float* __restrict__ dinv,
                                                const float* __restrict__ bias, float* __restrict__ agg,
                                                float* __restrict__ stats, int N) {
    const int lane = threadIdx.x & 63;
    const int wv = threadIdx.x >> 6;
    const int wid0 = blockIdx.x * 4 + wv;
    const int wstride = gridDim.x * 4;

    const float2* __restrict__ h2 = (const float2*)hW;
    const float2 b2 = ((const float2*)bias)[lane];

    float s0 = 0.f, s1 = 0.f, q0 = 0.f, q1 = 0.f;

    for (int n = wid0; n < N; n += wstride) {
        float sw = dinv[n];
        sw *= sw;
        float2 self = h2[(size_t)n * 64 + lane];
        float2 acc;
        acc.x = fmaf(self.x, sw, b2.x);
        acc.y = fmaf(self.y, sw, b2.y);
        const int e1 = rowend[n];
        for (int e = rowptr[n]; e < e1; ++e) {
            int s = csr_src[e];
            float w = csr_w[e];
            float2 v = h2[(size_t)s * 64 + lane];
            acc.x = fmaf(v.x, w, acc.x);
            acc.y = fmaf(v.y, w, acc.y);
        }
        ((float2*)agg)[(size_t)n * 64 + lane] = acc;
        s0 += acc.x;
        s1 += acc.y;
        q0 = fmaf(acc.x, acc.x, q0);
        q1 = fmaf(acc.y, acc.y, q1);
    }

    // block-level stats reduce: 4 waves -> 256 values -> atomics
    __shared__ float red[4][64][4];
    red[wv][lane][0] = s0;
    red[wv][lane][1] = s1;
    red[wv][lane][2] = q0;
    red[wv][lane][3] = q1;
    __syncthreads();
    const int t = threadIdx.x;
    const int l = t & 63, c = t >> 6;
    float v = red[0][l][c] + red[1][l][c] + red[2][l][c] + red[3][l][c];
    int f = 2 * l + (c & 1);
    int base = (c >> 1) ? HD : 0;
    unsafeAtomicAdd(&stats[base + f], v);
}

// ---------------- BN finalize: scale/shift from stats ----------------

__global__ __launch_bounds__(128) void k_bn_fin(const float* __restrict__ stats, const float* __restrict__ g,
                                                const float* __restrict__ be, float* __restrict__ scsh,
                                                float invN) {
    int f = threadIdx.x;  // 128 threads
    float mean = stats[f] * invN;
    float var = fmaf(-mean, mean, stats[HD + f] * invN);
    float sc = g[f] * rsqrtf(var + BN_EPS);
    scsh[f] = sc;
    scsh[HD + f] = fmaf(-mean, sc, be[f]);
}

// ---------------- decode: out[q] = dot(bn(h[u]), bn(h[v])) ----------------

__global__ __launch_bounds__(256) void k_decode(const float* __restrict__ h, const float* __restrict__ scsh,
                                                const int* __restrict__ qu, const int* __restrict__ qv,
                                                float* __restrict__ out, int Q) {
    int tid = blockIdx.x * 256 + threadIdx.x;
    int wid = tid >> 6;
    int lane = threadIdx.x & 63;
    if (wid >= Q) return;
    int u = qu[wid], v = qv[wid];
    float sc0 = scsh[lane], sh0 = scsh[HD + lane];
    float sc1 = scsh[64 + lane], sh1 = scsh[HD + 64 + lane];
    const float* ru = &h[(size_t)u * HD];
    const float* rv = &h[(size_t)v * HD];
    float a0 = fmaf(ru[lane], sc0, sh0);
    float b0 = fmaf(rv[lane], sc0, sh0);
    float a1 = fmaf(ru[64 + lane], sc1, sh1);
    float b1 = fmaf(rv[64 + lane], sc1, sh1);
    float p = a0 * b0 + a1 * b1;
#pragma unroll
    for (int off = 32; off; off >>= 1) p += __shfl_down(p, off);
    if (lane == 0) out[wid] = p;
}

// ---------------- launch ----------------

static inline size_t alignup(size_t x) { return (x + 511) & ~(size_t)511; }

extern "C" void kernel_launch(void* const* d_in, const int* in_sizes, int n_in,
                              void* d_out, int out_size, void* d_ws, size_t ws_size,
                              hipStream_t stream) {
    const float* x     = (const float*)d_in[0];
    const float* Wl[3]  = {(const float*)d_in[1], (const float*)d_in[5], (const float*)d_in[9]};
    const float* bl[3]  = {(const float*)d_in[2], (const float*)d_in[6], (const float*)d_in[10]};
    const float* gl[3]  = {(const float*)d_in[3], (const float*)d_in[7], (const float*)d_in[11]};
    const float* bel[3] = {(const float*)d_in[4], (const float*)d_in[8], (const float*)d_in[12]};
    const int* ei  = (const int*)d_in[13];
    const int* eli = (const int*)d_in[14];

    const int N = in_sizes[0] / HD;
    const int E = in_sizes[13] / 2;
    const int Q = in_sizes[14] / 2;
    const int* src = ei;
    const int* dst = ei + E;
    const int* qu = eli;
    const int* qv = eli + Q;
    float* out = (float*)d_out;

    char* ws = (char*)d_ws;
    size_t off = 0;
    float* dinv    = (float*)(ws + off); off = alignup(off + (size_t)N * 4);
    int*   cnt     = (int*)(ws + off);   off = alignup(off + (size_t)N * 4);
    int*   rowptr  = (int*)(ws + off);   off = alignup(off + (size_t)N * 4);
    int*   cursor  = (int*)(ws + off);   off = alignup(off + (size_t)N * 4);
    int*   bsum    = (int*)(ws + off);   off = alignup(off + 1024 * 4);
    float* stats   = (float*)(ws + off); off = alignup(off + 256 * 4);
    float* scsh0   = (float*)(ws + off); off = alignup(off + 256 * 4);
    float* scsh1   = (float*)(ws + off); off = alignup(off + 256 * 4);
    float* scsh2   = (float*)(ws + off); off = alignup(off + 256 * 4);
    int*   csr_src = (int*)(ws + off);   off = alignup(off + (size_t)E * 4);
    float* csr_w   = (float*)(ws + off); off = alignup(off + (size_t)E * 4);
    float* hA      = (float*)(ws + off); off = alignup(off + (size_t)N * HD * 4);
    float* hB      = (float*)(ws + off); off = alignup(off + (size_t)N * HD * 4);
    (void)ws_size; (void)n_in; (void)out_size;

    float* scshl[3] = {scsh0, scsh1, scsh2};
    const float invN = 1.0f / (float)N;
    const int NB = (N + 1023) / 1024;
    const int eg = (E + 255) / 256;

    // ---- CSR build (per call; deterministic work) ----
    hipMemsetAsync(cnt, 0, (size_t)N * 4, stream);
    k_count<<<eg, 256, 0, stream>>>(dst, cnt, E);
    k_dinv<<<(N + 255) / 256, 256, 0, stream>>>(cnt, dinv, N);
    k_scan_a<<<NB, 256, 0, stream>>>(cnt, bsum, N);
    k_scan_b<<<1, 64, 0, stream>>>(bsum, NB);
    k_scan_c<<<NB, 256, 0, stream>>>(cnt, bsum, rowptr, N);
    hipMemcpyAsync(cursor, rowptr, (size_t)N * 4, hipMemcpyDeviceToDevice, stream);
    k_fill<<<eg, 256, 0, stream>>>(src, dst, dinv, cursor, csr_src, csr_w, E);

    // ---- 3 GCN layers ----
    const float* hin = x;
    for (int l = 0; l < 3; ++l) {
        k_gemm<<<(N + 31) / 32, 256, 0, stream>>>(hin, Wl[l], hB, N, l ? scshl[l - 1] : nullptr);
        hipMemsetAsync(stats, 0, 256 * 4, stream);
        k_gather<<<GATHER_BLOCKS, 256, 0, stream>>>(hB, rowptr, cursor, csr_src, csr_w, dinv,
                                                    bl[l], hA, stats, N);
        k_bn_fin<<<1, HD, 0, stream>>>(stats, gl[l], bel[l], scshl[l], invN);
        hin = hA;
    }

    k_decode<<<(Q + 3) / 4, 256, 0, stream>>>(hA, scsh2, qu, qv, out, Q);
}

// Round 3
// 829.530 us; speedup vs baseline: 1.8781x; 1.0355x over previous
//
#include <hip/hip_runtime.h>

#define HD 128
#define BN_EPS 1e-5f

// ---------------- CSR build: count / dinv / scan / fill ----------------

__global__ __launch_bounds__(256) void k_count(const int* __restrict__ dst, int* __restrict__ cnt, int E) {
    int e = blockIdx.x * 256 + threadIdx.x;
    if (e < E) atomicAdd(&cnt[dst[e]], 1);
}

__global__ __launch_bounds__(256) void k_dinv(const int* __restrict__ cnt, float* __restrict__ dinv, int N) {
    int n = blockIdx.x * 256 + threadIdx.x;
    if (n < N) dinv[n] = rsqrtf((float)cnt[n] + 1.0f);
}

// block partial sums over 1024-element chunks
__global__ __launch_bounds__(256) void k_scan_a(const int* __restrict__ cnt, int* __restrict__ bsum, int N) {
    __shared__ int s[256];
    int base = blockIdx.x * 1024 + threadIdx.x * 4;
    int v = 0;
#pragma unroll
    for (int j = 0; j < 4; ++j) {
        int idx = base + j;
        if (idx < N) v += cnt[idx];
    }
    s[threadIdx.x] = v;
    __syncthreads();
    for (int o = 128; o; o >>= 1) {
        if (threadIdx.x < (unsigned)o) s[threadIdx.x] += s[threadIdx.x + o];
        __syncthreads();
    }
    if (threadIdx.x == 0) bsum[blockIdx.x] = s[0];
}

// serial exclusive scan of block sums (NB ~ 98, trivial)
__global__ void k_scan_b(int* __restrict__ bsum, int NB) {
    if (threadIdx.x == 0 && blockIdx.x == 0) {
        int acc = 0;
        for (int i = 0; i < NB; ++i) {
            int v = bsum[i];
            bsum[i] = acc;
            acc += v;
        }
    }
}

// per-chunk exclusive scan + block offset -> rowptr
__global__ __launch_bounds__(256) void k_scan_c(const int* __restrict__ cnt, const int* __restrict__ bsum,
                                                int* __restrict__ rowptr, int N) {
    __shared__ int s[256];
    const int t = threadIdx.x;
    int base = blockIdx.x * 1024 + t * 4;
    int v0 = 0, v1 = 0, v2 = 0, v3 = 0;
    if (base + 0 < N) v0 = cnt[base + 0];
    if (base + 1 < N) v1 = cnt[base + 1];
    if (base + 2 < N) v2 = cnt[base + 2];
    if (base + 3 < N) v3 = cnt[base + 3];
    int ts = v0 + v1 + v2 + v3;
    s[t] = ts;
    __syncthreads();
    for (int o = 1; o < 256; o <<= 1) {
        int add = (t >= o) ? s[t - o] : 0;
        __syncthreads();
        s[t] += add;
        __syncthreads();
    }
    int excl = s[t] - ts + bsum[blockIdx.x];
    if (base + 0 < N) rowptr[base + 0] = excl;
    if (base + 1 < N) rowptr[base + 1] = excl + v0;
    if (base + 2 < N) rowptr[base + 2] = excl + v0 + v1;
    if (base + 3 < N) rowptr[base + 3] = excl + v0 + v1 + v2;
}

// cursor starts as copy of rowptr; fill bumps it to row end
__global__ __launch_bounds__(256) void k_fill(const int* __restrict__ src, const int* __restrict__ dst,
                                              const float* __restrict__ dinv, int* __restrict__ cursor,
                                              int* __restrict__ csr_src, float* __restrict__ csr_w, int E) {
    int e = blockIdx.x * 256 + threadIdx.x;
    if (e >= E) return;
    int s = src[e], d = dst[e];
    int pos = atomicAdd(&cursor[d], 1);
    csr_src[pos] = s;
    csr_w[pos] = dinv[s] * dinv[d];
}

// ---------------- GEMM: C[N,128] = bn(A)[N,128] @ W[128,128] ----------------
// scsh != nullptr: apply per-feature scale/shift + ReLU to A on load (fused BN of prev layer).

__global__ __launch_bounds__(256) void k_gemm(const float* __restrict__ A, const float* __restrict__ W,
                                              float* __restrict__ C, int N, const float* __restrict__ scsh) {
    __shared__ float As[32][HD];
    __shared__ float Ws[HD][HD];
    const int t = threadIdx.x;
    const int row0 = blockIdx.x * 32;

    for (int i = t; i < HD * HD / 4; i += 256)
        ((float4*)Ws)[i] = ((const float4*)W)[i];
    for (int i = t; i < 32 * HD / 4; i += 256) {
        int r = i >> 5, q = i & 31;
        int gr = row0 + r;
        float4 v = make_float4(0.f, 0.f, 0.f, 0.f);
        if (gr < N) v = ((const float4*)A)[(size_t)gr * 32 + q];
        if (scsh) {
            const float4 sc = ((const float4*)scsh)[q];
            const float4 sh = ((const float4*)scsh)[32 + q];
            v.x = fmaxf(fmaf(v.x, sc.x, sh.x), 0.f);
            v.y = fmaxf(fmaf(v.y, sc.y, sh.y), 0.f);
            v.z = fmaxf(fmaf(v.z, sc.z, sh.z), 0.f);
            v.w = fmaxf(fmaf(v.w, sc.w, sh.w), 0.f);
        }
        ((float4*)As)[i] = v;
    }
    __syncthreads();

    const int tx = t & 31, ty = t >> 5;
    const int c0 = tx * 4, r0 = ty * 4;
    float acc[4][4] = {};
#pragma unroll 8
    for (int k = 0; k < HD; ++k) {
        const float4 w = *(const float4*)&Ws[k][c0];
#pragma unroll
        for (int i = 0; i < 4; ++i) {
            const float a = As[r0 + i][k];
            acc[i][0] = fmaf(a, w.x, acc[i][0]);
            acc[i][1] = fmaf(a, w.y, acc[i][1]);
            acc[i][2] = fmaf(a, w.z, acc[i][2]);
            acc[i][3] = fmaf(a, w.w, acc[i][3]);
        }
    }
#pragma unroll
    for (int i = 0; i < 4; ++i) {
        int gr = row0 + r0 + i;
        if (gr < N)
            *(float4*)&C[(size_t)gr * HD + c0] =
                make_float4(acc[i][0], acc[i][1], acc[i][2], acc[i][3]);
    }
}

// ---------------- fused aggregation: gather + self-loop + bias + BN stats ----------------
// one wave per node (grid-stride); lane holds features {2*lane, 2*lane+1}
// 2048 blocks = 8 blocks/CU = 32 waves/CU (occupancy cap); edge loop unrolled x4 for MLP.

#define GATHER_BLOCKS 2048

__global__ __launch_bounds__(256) void k_gather(const float* __restrict__ hW, const int* __restrict__ rowptr,
                                                const int* __restrict__ rowend, const int* __restrict__ csr_src,
                                                const float* __restrict__ csr_w, const float* __restrict__ dinv,
                                                const float* __restrict__ bias, float* __restrict__ agg,
                                                float* __restrict__ stats, int N) {
    const int lane = threadIdx.x & 63;
    const int wv = threadIdx.x >> 6;
    const int wid0 = blockIdx.x * 4 + wv;
    const int wstride = gridDim.x * 4;

    const float2* __restrict__ h2 = (const float2*)hW;
    const float2 b2 = ((const float2*)bias)[lane];

    float s0 = 0.f, s1 = 0.f, q0 = 0.f, q1 = 0.f;

    for (int n = wid0; n < N; n += wstride) {
        float sw = dinv[n];
        sw *= sw;
        float2 self = h2[(size_t)n * 64 + lane];
        float2 acc;
        acc.x = fmaf(self.x, sw, b2.x);
        acc.y = fmaf(self.y, sw, b2.y);
        int e = rowptr[n];
        const int e1 = rowend[n];
        // unrolled x4: batch index/weight loads, then 4 independent row gathers
        for (; e + 4 <= e1; e += 4) {
            int i0 = csr_src[e + 0], i1 = csr_src[e + 1], i2 = csr_src[e + 2], i3 = csr_src[e + 3];
            float w0 = csr_w[e + 0], w1 = csr_w[e + 1], w2 = csr_w[e + 2], w3 = csr_w[e + 3];
            float2 v0 = h2[(size_t)i0 * 64 + lane];
            float2 v1 = h2[(size_t)i1 * 64 + lane];
            float2 v2 = h2[(size_t)i2 * 64 + lane];
            float2 v3 = h2[(size_t)i3 * 64 + lane];
            acc.x = fmaf(v0.x, w0, acc.x);
            acc.y = fmaf(v0.y, w0, acc.y);
            acc.x = fmaf(v1.x, w1, acc.x);
            acc.y = fmaf(v1.y, w1, acc.y);
            acc.x = fmaf(v2.x, w2, acc.x);
            acc.y = fmaf(v2.y, w2, acc.y);
            acc.x = fmaf(v3.x, w3, acc.x);
            acc.y = fmaf(v3.y, w3, acc.y);
        }
        for (; e < e1; ++e) {
            int s = csr_src[e];
            float w = csr_w[e];
            float2 v = h2[(size_t)s * 64 + lane];
            acc.x = fmaf(v.x, w, acc.x);
            acc.y = fmaf(v.y, w, acc.y);
        }
        ((float2*)agg)[(size_t)n * 64 + lane] = acc;
        s0 += acc.x;
        s1 += acc.y;
        q0 = fmaf(acc.x, acc.x, q0);
        q1 = fmaf(acc.y, acc.y, q1);
    }

    // block-level stats reduce: 4 waves -> 256 values -> atomics
    __shared__ float red[4][64][4];
    red[wv][lane][0] = s0;
    red[wv][lane][1] = s1;
    red[wv][lane][2] = q0;
    red[wv][lane][3] = q1;
    __syncthreads();
    const int t = threadIdx.x;
    const int l = t & 63, c = t >> 6;
    float v = red[0][l][c] + red[1][l][c] + red[2][l][c] + red[3][l][c];
    int f = 2 * l + (c & 1);
    int base = (c >> 1) ? HD : 0;
    unsafeAtomicAdd(&stats[base + f], v);
}

// ---------------- BN finalize: scale/shift from stats ----------------

__global__ __launch_bounds__(128) void k_bn_fin(const float* __restrict__ stats, const float* __restrict__ g,
                                                const float* __restrict__ be, float* __restrict__ scsh,
                                                float invN) {
    int f = threadIdx.x;  // 128 threads
    float mean = stats[f] * invN;
    float var = fmaf(-mean, mean, stats[HD + f] * invN);
    float sc = g[f] * rsqrtf(var + BN_EPS);
    scsh[f] = sc;
    scsh[HD + f] = fmaf(-mean, sc, be[f]);
}

// ---------------- decode: out[q] = dot(bn(h[u]), bn(h[v])) ----------------

__global__ __launch_bounds__(256) void k_decode(const float* __restrict__ h, const float* __restrict__ scsh,
                                                const int* __restrict__ qu, const int* __restrict__ qv,
                                                float* __restrict__ out, int Q) {
    int tid = blockIdx.x * 256 + threadIdx.x;
    int wid = tid >> 6;
    int lane = threadIdx.x & 63;
    if (wid >= Q) return;
    int u = qu[wid], v = qv[wid];
    float sc0 = scsh[lane], sh0 = scsh[HD + lane];
    float sc1 = scsh[64 + lane], sh1 = scsh[HD + 64 + lane];
    const float* ru = &h[(size_t)u * HD];
    const float* rv = &h[(size_t)v * HD];
    float a0 = fmaf(ru[lane], sc0, sh0);
    float b0 = fmaf(rv[lane], sc0, sh0);
    float a1 = fmaf(ru[64 + lane], sc1, sh1);
    float b1 = fmaf(rv[64 + lane], sc1, sh1);
    float p = a0 * b0 + a1 * b1;
#pragma unroll
    for (int off = 32; off; off >>= 1) p += __shfl_down(p, off);
    if (lane == 0) out[wid] = p;
}

// ---------------- launch ----------------

static inline size_t alignup(size_t x) { return (x + 511) & ~(size_t)511; }

extern "C" void kernel_launch(void* const* d_in, const int* in_sizes, int n_in,
                              void* d_out, int out_size, void* d_ws, size_t ws_size,
                              hipStream_t stream) {
    const float* x     = (const float*)d_in[0];
    const float* Wl[3]  = {(const float*)d_in[1], (const float*)d_in[5], (const float*)d_in[9]};
    const float* bl[3]  = {(const float*)d_in[2], (const float*)d_in[6], (const float*)d_in[10]};
    const float* gl[3]  = {(const float*)d_in[3], (const float*)d_in[7], (const float*)d_in[11]};
    const float* bel[3] = {(const float*)d_in[4], (const float*)d_in[8], (const float*)d_in[12]};
    const int* ei  = (const int*)d_in[13];
    const int* eli = (const int*)d_in[14];

    const int N = in_sizes[0] / HD;
    const int E = in_sizes[13] / 2;
    const int Q = in_sizes[14] / 2;
    const int* src = ei;
    const int* dst = ei + E;
    const int* qu = eli;
    const int* qv = eli + Q;
    float* out = (float*)d_out;

    char* ws = (char*)d_ws;
    size_t off = 0;
    float* dinv    = (float*)(ws + off); off = alignup(off + (size_t)N * 4);
    int*   cnt     = (int*)(ws + off);   off = alignup(off + (size_t)N * 4);
    int*   rowptr  = (int*)(ws + off);   off = alignup(off + (size_t)N * 4);
    int*   cursor  = (int*)(ws + off);   off = alignup(off + (size_t)N * 4);
    int*   bsum    = (int*)(ws + off);   off = alignup(off + 1024 * 4);
    float* stats   = (float*)(ws + off); off = alignup(off + 256 * 4);
    float* scsh0   = (float*)(ws + off); off = alignup(off + 256 * 4);
    float* scsh1   = (float*)(ws + off); off = alignup(off + 256 * 4);
    float* scsh2   = (float*)(ws + off); off = alignup(off + 256 * 4);
    int*   csr_src = (int*)(ws + off);   off = alignup(off + (size_t)E * 4);
    float* csr_w   = (float*)(ws + off); off = alignup(off + (size_t)E * 4);
    float* hA      = (float*)(ws + off); off = alignup(off + (size_t)N * HD * 4);
    float* hB      = (float*)(ws + off); off = alignup(off + (size_t)N * HD * 4);
    (void)ws_size; (void)n_in; (void)out_size;

    float* scshl[3] = {scsh0, scsh1, scsh2};
    const float invN = 1.0f / (float)N;
    const int NB = (N + 1023) / 1024;
    const int eg = (E + 255) / 256;

    // ---- CSR build (per call; deterministic work) ----
    hipMemsetAsync(cnt, 0, (size_t)N * 4, stream);
    k_count<<<eg, 256, 0, stream>>>(dst, cnt, E);
    k_dinv<<<(N + 255) / 256, 256, 0, stream>>>(cnt, dinv, N);
    k_scan_a<<<NB, 256, 0, stream>>>(cnt, bsum, N);
    k_scan_b<<<1, 64, 0, stream>>>(bsum, NB);
    k_scan_c<<<NB, 256, 0, stream>>>(cnt, bsum, rowptr, N);
    hipMemcpyAsync(cursor, rowptr, (size_t)N * 4, hipMemcpyDeviceToDevice, stream);
    k_fill<<<eg, 256, 0, stream>>>(src, dst, dinv, cursor, csr_src, csr_w, E);

    // ---- 3 GCN layers ----
    const float* hin = x;
    for (int l = 0; l < 3; ++l) {
        k_gemm<<<(N + 31) / 32, 256, 0, stream>>>(hin, Wl[l], hB, N, l ? scshl[l - 1] : nullptr);
        hipMemsetAsync(stats, 0, 256 * 4, stream);
        k_gather<<<GATHER_BLOCKS, 256, 0, stream>>>(hB, rowptr, cursor, csr_src, csr_w, dinv,
                                                    bl[l], hA, stats, N);
        k_bn_fin<<<1, HD, 0, stream>>>(stats, gl[l], bel[l], scshl[l], invN);
        hin = hA;
    }

    k_decode<<<(Q + 3) / 4, 256, 0, stream>>>(hA, scsh2, qu, qv, out, Q);
}

// Round 4
// 777.457 us; speedup vs baseline: 2.0039x; 1.0670x over previous
//
#include <hip/hip_runtime.h>

#define HD 128
#define BN_EPS 1e-5f

typedef unsigned int uint;

// bf16x2 packed in a uint: lo half = feature 2*lane, hi half = feature 2*lane+1
__device__ __forceinline__ float bf_lo(uint u) { return __uint_as_float(u << 16); }
__device__ __forceinline__ float bf_hi(uint u) { return __uint_as_float(u & 0xffff0000u); }
__device__ __forceinline__ uint bf_round(float f) {  // RNE to bf16 bits (in high 16)
    uint u = __float_as_uint(f);
    return (u + 0x7fffu + ((u >> 16) & 1u)) & 0xffff0000u;
}
__device__ __forceinline__ uint pack_bf2(float a, float b) {
    return (bf_round(a) >> 16) | bf_round(b);
}

// ---------------- CSR build: count / dinv / scan / fill ----------------

__global__ __launch_bounds__(256) void k_count(const int* __restrict__ dst, int* __restrict__ cnt, int E) {
    int e = blockIdx.x * 256 + threadIdx.x;
    if (e < E) atomicAdd(&cnt[dst[e]], 1);
}

__global__ __launch_bounds__(256) void k_dinv(const int* __restrict__ cnt, float* __restrict__ dinv, int N) {
    int n = blockIdx.x * 256 + threadIdx.x;
    if (n < N) dinv[n] = rsqrtf((float)cnt[n] + 1.0f);
}

__global__ __launch_bounds__(256) void k_scan_a(const int* __restrict__ cnt, int* __restrict__ bsum, int N) {
    __shared__ int s[256];
    int base = blockIdx.x * 1024 + threadIdx.x * 4;
    int v = 0;
#pragma unroll
    for (int j = 0; j < 4; ++j) {
        int idx = base + j;
        if (idx < N) v += cnt[idx];
    }
    s[threadIdx.x] = v;
    __syncthreads();
    for (int o = 128; o; o >>= 1) {
        if (threadIdx.x < (unsigned)o) s[threadIdx.x] += s[threadIdx.x + o];
        __syncthreads();
    }
    if (threadIdx.x == 0) bsum[blockIdx.x] = s[0];
}

__global__ void k_scan_b(int* __restrict__ bsum, int NB) {
    if (threadIdx.x == 0 && blockIdx.x == 0) {
        int acc = 0;
        for (int i = 0; i < NB; ++i) {
            int v = bsum[i];
            bsum[i] = acc;
            acc += v;
        }
    }
}

__global__ __launch_bounds__(256) void k_scan_c(const int* __restrict__ cnt, const int* __restrict__ bsum,
                                                int* __restrict__ rowptr, int N) {
    __shared__ int s[256];
    const int t = threadIdx.x;
    int base = blockIdx.x * 1024 + t * 4;
    int v0 = 0, v1 = 0, v2 = 0, v3 = 0;
    if (base + 0 < N) v0 = cnt[base + 0];
    if (base + 1 < N) v1 = cnt[base + 1];
    if (base + 2 < N) v2 = cnt[base + 2];
    if (base + 3 < N) v3 = cnt[base + 3];
    int ts = v0 + v1 + v2 + v3;
    s[t] = ts;
    __syncthreads();
    for (int o = 1; o < 256; o <<= 1) {
        int add = (t >= o) ? s[t - o] : 0;
        __syncthreads();
        s[t] += add;
        __syncthreads();
    }
    int excl = s[t] - ts + bsum[blockIdx.x];
    if (base + 0 < N) rowptr[base + 0] = excl;
    if (base + 1 < N) rowptr[base + 1] = excl + v0;
    if (base + 2 < N) rowptr[base + 2] = excl + v0 + v1;
    if (base + 3 < N) rowptr[base + 3] = excl + v0 + v1 + v2;
}

__global__ __launch_bounds__(256) void k_fill(const int* __restrict__ src, const int* __restrict__ dst,
                                              const float* __restrict__ dinv, int* __restrict__ cursor,
                                              int* __restrict__ csr_src, float* __restrict__ csr_w, int E) {
    int e = blockIdx.x * 256 + threadIdx.x;
    if (e >= E) return;
    int s = src[e], d = dst[e];
    int pos = atomicAdd(&cursor[d], 1);
    csr_src[pos] = s;
    csr_w[pos] = dinv[s] * dinv[d];
}

// ---------------- GEMM: C_bf16[N,128] = bn(A)[N,128] @ W[128,128] ----------------

__global__ __launch_bounds__(256) void k_gemm(const float* __restrict__ A, const float* __restrict__ W,
                                              uint* __restrict__ C, int N, const float* __restrict__ scsh) {
    __shared__ float As[32][HD];
    __shared__ float Ws[HD][HD];
    const int t = threadIdx.x;
    const int row0 = blockIdx.x * 32;

    for (int i = t; i < HD * HD / 4; i += 256)
        ((float4*)Ws)[i] = ((const float4*)W)[i];
    for (int i = t; i < 32 * HD / 4; i += 256) {
        int r = i >> 5, q = i & 31;
        int gr = row0 + r;
        float4 v = make_float4(0.f, 0.f, 0.f, 0.f);
        if (gr < N) v = ((const float4*)A)[(size_t)gr * 32 + q];
        if (scsh) {
            const float4 sc = ((const float4*)scsh)[q];
            const float4 sh = ((const float4*)scsh)[32 + q];
            v.x = fmaxf(fmaf(v.x, sc.x, sh.x), 0.f);
            v.y = fmaxf(fmaf(v.y, sc.y, sh.y), 0.f);
            v.z = fmaxf(fmaf(v.z, sc.z, sh.z), 0.f);
            v.w = fmaxf(fmaf(v.w, sc.w, sh.w), 0.f);
        }
        ((float4*)As)[i] = v;
    }
    __syncthreads();

    const int tx = t & 31, ty = t >> 5;
    const int c0 = tx * 4, r0 = ty * 4;
    float acc[4][4] = {};
#pragma unroll 8
    for (int k = 0; k < HD; ++k) {
        const float4 w = *(const float4*)&Ws[k][c0];
#pragma unroll
        for (int i = 0; i < 4; ++i) {
            const float a = As[r0 + i][k];
            acc[i][0] = fmaf(a, w.x, acc[i][0]);
            acc[i][1] = fmaf(a, w.y, acc[i][1]);
            acc[i][2] = fmaf(a, w.z, acc[i][2]);
            acc[i][3] = fmaf(a, w.w, acc[i][3]);
        }
    }
#pragma unroll
    for (int i = 0; i < 4; ++i) {
        int gr = row0 + r0 + i;
        if (gr < N) {
            uint2 p;
            p.x = pack_bf2(acc[i][0], acc[i][1]);
            p.y = pack_bf2(acc[i][2], acc[i][3]);
            *(uint2*)&C[(size_t)gr * 64 + (c0 >> 1)] = p;
        }
    }
}

// ---------------- fused aggregation: bf16 gather + self-loop + bias + BN stats ----------------
// one wave per node (grid-stride); lane holds features {2*lane, 2*lane+1} (one packed uint)

#define GATHER_BLOCKS 2048

template <int OUT_BF16>
__global__ __launch_bounds__(256) void k_gather(const uint* __restrict__ hW, const int* __restrict__ rowptr,
                                                const int* __restrict__ rowend, const int* __restrict__ csr_src,
                                                const float* __restrict__ csr_w, const float* __restrict__ dinv,
                                                const float* __restrict__ bias, void* __restrict__ agg,
                                                float* __restrict__ stats, int N) {
    const int lane = threadIdx.x & 63;
    const int wv = threadIdx.x >> 6;
    const int wid0 = blockIdx.x * 4 + wv;
    const int wstride = gridDim.x * 4;

    const float2 b2 = ((const float2*)bias)[lane];

    float s0 = 0.f, s1 = 0.f, q0 = 0.f, q1 = 0.f;

    for (int n = wid0; n < N; n += wstride) {
        float sw = dinv[n];
        sw *= sw;
        uint self = hW[(size_t)n * 64 + lane];
        float2 acc;
        acc.x = fmaf(bf_lo(self), sw, b2.x);
        acc.y = fmaf(bf_hi(self), sw, b2.y);
        int e = rowptr[n];
        const int e1 = rowend[n];
        // unrolled x8: batch index/weight loads, then 8 independent row gathers (1 dword/lane each)
        for (; e + 8 <= e1; e += 8) {
            int idx[8];
            float w[8];
            uint r[8];
#pragma unroll
            for (int j = 0; j < 8; ++j) {
                idx[j] = csr_src[e + j];
                w[j] = csr_w[e + j];
            }
#pragma unroll
            for (int j = 0; j < 8; ++j) r[j] = hW[(size_t)idx[j] * 64 + lane];
#pragma unroll
            for (int j = 0; j < 8; ++j) {
                acc.x = fmaf(bf_lo(r[j]), w[j], acc.x);
                acc.y = fmaf(bf_hi(r[j]), w[j], acc.y);
            }
        }
        for (; e < e1; ++e) {
            int s = csr_src[e];
            float w = csr_w[e];
            uint v = hW[(size_t)s * 64 + lane];
            acc.x = fmaf(bf_lo(v), w, acc.x);
            acc.y = fmaf(bf_hi(v), w, acc.y);
        }
        if (OUT_BF16)
            ((uint*)agg)[(size_t)n * 64 + lane] = pack_bf2(acc.x, acc.y);
        else
            ((float2*)agg)[(size_t)n * 64 + lane] = acc;
        s0 += acc.x;
        s1 += acc.y;
        q0 = fmaf(acc.x, acc.x, q0);
        q1 = fmaf(acc.y, acc.y, q1);
    }

    // block-level stats reduce: 4 waves -> 256 values -> atomics
    __shared__ float red[4][64][4];
    red[wv][lane][0] = s0;
    red[wv][lane][1] = s1;
    red[wv][lane][2] = q0;
    red[wv][lane][3] = q1;
    __syncthreads();
    const int t = threadIdx.x;
    const int l = t & 63, c = t >> 6;
    float v = red[0][l][c] + red[1][l][c] + red[2][l][c] + red[3][l][c];
    int f = 2 * l + (c & 1);
    int base = (c >> 1) ? HD : 0;
    unsafeAtomicAdd(&stats[base + f], v);
}

// ---------------- BN finalize ----------------

__global__ __launch_bounds__(128) void k_bn_fin(const float* __restrict__ stats, const float* __restrict__ g,
                                                const float* __restrict__ be, float* __restrict__ scsh,
                                                float invN) {
    int f = threadIdx.x;
    float mean = stats[f] * invN;
    float var = fmaf(-mean, mean, stats[HD + f] * invN);
    float sc = g[f] * rsqrtf(var + BN_EPS);
    scsh[f] = sc;
    scsh[HD + f] = fmaf(-mean, sc, be[f]);
}

// ---------------- decode: out[q] = dot(bn(h[u]), bn(h[v])), h in bf16 ----------------

__global__ __launch_bounds__(256) void k_decode(const uint* __restrict__ h, const float* __restrict__ scsh,
                                                const int* __restrict__ qu, const int* __restrict__ qv,
                                                float* __restrict__ out, int Q) {
    int tid = blockIdx.x * 256 + threadIdx.x;
    int wid = tid >> 6;
    int lane = threadIdx.x & 63;
    if (wid >= Q) return;
    int u = qu[wid], v = qv[wid];
    float2 sc = ((const float2*)scsh)[lane];
    float2 sh = ((const float2*)(scsh + HD))[lane];
    uint a = h[(size_t)u * 64 + lane];
    uint b = h[(size_t)v * 64 + lane];
    float a0 = fmaf(bf_lo(a), sc.x, sh.x);
    float b0 = fmaf(bf_lo(b), sc.x, sh.x);
    float a1 = fmaf(bf_hi(a), sc.y, sh.y);
    float b1 = fmaf(bf_hi(b), sc.y, sh.y);
    float p = a0 * b0 + a1 * b1;
#pragma unroll
    for (int off = 32; off; off >>= 1) p += __shfl_down(p, off);
    if (lane == 0) out[wid] = p;
}

// ---------------- launch ----------------

static inline size_t alignup(size_t x) { return (x + 511) & ~(size_t)511; }

extern "C" void kernel_launch(void* const* d_in, const int* in_sizes, int n_in,
                              void* d_out, int out_size, void* d_ws, size_t ws_size,
                              hipStream_t stream) {
    const float* x     = (const float*)d_in[0];
    const float* Wl[3]  = {(const float*)d_in[1], (const float*)d_in[5], (const float*)d_in[9]};
    const float* bl[3]  = {(const float*)d_in[2], (const float*)d_in[6], (const float*)d_in[10]};
    const float* gl[3]  = {(const float*)d_in[3], (const float*)d_in[7], (const float*)d_in[11]};
    const float* bel[3] = {(const float*)d_in[4], (const float*)d_in[8], (const float*)d_in[12]};
    const int* ei  = (const int*)d_in[13];
    const int* eli = (const int*)d_in[14];

    const int N = in_sizes[0] / HD;
    const int E = in_sizes[13] / 2;
    const int Q = in_sizes[14] / 2;
    const int* src = ei;
    const int* dst = ei + E;
    const int* qu = eli;
    const int* qv = eli + Q;
    float* out = (float*)d_out;

    char* ws = (char*)d_ws;
    size_t off = 0;
    float* dinv    = (float*)(ws + off); off = alignup(off + (size_t)N * 4);
    int*   cnt     = (int*)(ws + off);   off = alignup(off + (size_t)N * 4);
    int*   rowptr  = (int*)(ws + off);   off = alignup(off + (size_t)N * 4);
    int*   cursor  = (int*)(ws + off);   off = alignup(off + (size_t)N * 4);
    int*   bsum    = (int*)(ws + off);   off = alignup(off + 1024 * 4);
    float* stats   = (float*)(ws + off); off = alignup(off + 256 * 4);
    float* scsh0   = (float*)(ws + off); off = alignup(off + 256 * 4);
    float* scsh1   = (float*)(ws + off); off = alignup(off + 256 * 4);
    float* scsh2   = (float*)(ws + off); off = alignup(off + 256 * 4);
    int*   csr_src = (int*)(ws + off);   off = alignup(off + (size_t)E * 4);
    float* csr_w   = (float*)(ws + off); off = alignup(off + (size_t)E * 4);
    uint*  hB      = (uint*)(ws + off);  off = alignup(off + (size_t)N * HD * 2);  // bf16 gemm out
    float* hA      = (float*)(ws + off); off = alignup(off + (size_t)N * HD * 4);  // f32 agg out (l=0,1)
    uint*  hC      = (uint*)(ws + off);  off = alignup(off + (size_t)N * HD * 2);  // bf16 agg out (l=2)
    (void)ws_size; (void)n_in; (void)out_size;

    float* scshl[3] = {scsh0, scsh1, scsh2};
    const float invN = 1.0f / (float)N;
    const int NB = (N + 1023) / 1024;
    const int eg = (E + 255) / 256;

    // ---- CSR build ----
    hipMemsetAsync(cnt, 0, (size_t)N * 4, stream);
    k_count<<<eg, 256, 0, stream>>>(dst, cnt, E);
    k_dinv<<<(N + 255) / 256, 256, 0, stream>>>(cnt, dinv, N);
    k_scan_a<<<NB, 256, 0, stream>>>(cnt, bsum, N);
    k_scan_b<<<1, 64, 0, stream>>>(bsum, NB);
    k_scan_c<<<NB, 256, 0, stream>>>(cnt, bsum, rowptr, N);
    hipMemcpyAsync(cursor, rowptr, (size_t)N * 4, hipMemcpyDeviceToDevice, stream);
    k_fill<<<eg, 256, 0, stream>>>(src, dst, dinv, cursor, csr_src, csr_w, E);

    // ---- 3 GCN layers ----
    const float* hin = x;
    for (int l = 0; l < 3; ++l) {
        k_gemm<<<(N + 31) / 32, 256, 0, stream>>>(hin, Wl[l], hB, N, l ? scshl[l - 1] : nullptr);
        hipMemsetAsync(stats, 0, 256 * 4, stream);
        if (l < 2)
            k_gather<0><<<GATHER_BLOCKS, 256, 0, stream>>>(hB, rowptr, cursor, csr_src, csr_w, dinv,
                                                           bl[l], hA, stats, N);
        else
            k_gather<1><<<GATHER_BLOCKS, 256, 0, stream>>>(hB, rowptr, cursor, csr_src, csr_w, dinv,
                                                           bl[l], hC, stats, N);
        k_bn_fin<<<1, HD, 0, stream>>>(stats, gl[l], bel[l], scshl[l], invN);
        hin = hA;
    }

    k_decode<<<(Q + 3) / 4, 256, 0, stream>>>(hC, scsh2, qu, qv, out, Q);
}

// Round 5
// 577.394 us; speedup vs baseline: 2.6982x; 1.3465x over previous
//
#include <hip/hip_runtime.h>

#define HD 128
#define BN_EPS 1e-5f

typedef unsigned int uint;

// bf16x2 packed in a uint: lo half = even feature, hi half = odd feature
__device__ __forceinline__ float bf_lo(uint u) { return __uint_as_float(u << 16); }
__device__ __forceinline__ float bf_hi(uint u) { return __uint_as_float(u & 0xffff0000u); }
__device__ __forceinline__ uint bf_round(float f) {  // RNE to bf16 bits (in high 16)
    uint u = __float_as_uint(f);
    return (u + 0x7fffu + ((u >> 16) & 1u)) & 0xffff0000u;
}
__device__ __forceinline__ uint pack_bf2(float a, float b) {
    return (bf_round(a) >> 16) | bf_round(b);
}
__device__ __forceinline__ void unpack8(uint4 u, float* f) {
    f[0] = bf_lo(u.x); f[1] = bf_hi(u.x);
    f[2] = bf_lo(u.y); f[3] = bf_hi(u.y);
    f[4] = bf_lo(u.z); f[5] = bf_hi(u.z);
    f[6] = bf_lo(u.w); f[7] = bf_hi(u.w);
}

// ---------------- CSR build: count / dinv / scan / fill ----------------

__global__ __launch_bounds__(256) void k_count(const int* __restrict__ dst, int* __restrict__ cnt, int E) {
    int e = blockIdx.x * 256 + threadIdx.x;
    if (e < E) atomicAdd(&cnt[dst[e]], 1);
}

__global__ __launch_bounds__(256) void k_dinv(const int* __restrict__ cnt, float* __restrict__ dinv, int N) {
    int n = blockIdx.x * 256 + threadIdx.x;
    if (n < N) dinv[n] = rsqrtf((float)cnt[n] + 1.0f);
}

__global__ __launch_bounds__(256) void k_scan_a(const int* __restrict__ cnt, int* __restrict__ bsum, int N) {
    __shared__ int s[256];
    int base = blockIdx.x * 1024 + threadIdx.x * 4;
    int v = 0;
#pragma unroll
    for (int j = 0; j < 4; ++j) {
        int idx = base + j;
        if (idx < N) v += cnt[idx];
    }
    s[threadIdx.x] = v;
    __syncthreads();
    for (int o = 128; o; o >>= 1) {
        if (threadIdx.x < (unsigned)o) s[threadIdx.x] += s[threadIdx.x + o];
        __syncthreads();
    }
    if (threadIdx.x == 0) bsum[blockIdx.x] = s[0];
}

__global__ void k_scan_b(int* __restrict__ bsum, int NB) {
    if (threadIdx.x == 0 && blockIdx.x == 0) {
        int acc = 0;
        for (int i = 0; i < NB; ++i) {
            int v = bsum[i];
            bsum[i] = acc;
            acc += v;
        }
    }
}

__global__ __launch_bounds__(256) void k_scan_c(const int* __restrict__ cnt, const int* __restrict__ bsum,
                                                int* __restrict__ rowptr, int N) {
    __shared__ int s[256];
    const int t = threadIdx.x;
    int base = blockIdx.x * 1024 + t * 4;
    int v0 = 0, v1 = 0, v2 = 0, v3 = 0;
    if (base + 0 < N) v0 = cnt[base + 0];
    if (base + 1 < N) v1 = cnt[base + 1];
    if (base + 2 < N) v2 = cnt[base + 2];
    if (base + 3 < N) v3 = cnt[base + 3];
    int ts = v0 + v1 + v2 + v3;
    s[t] = ts;
    __syncthreads();
    for (int o = 1; o < 256; o <<= 1) {
        int add = (t >= o) ? s[t - o] : 0;
        __syncthreads();
        s[t] += add;
        __syncthreads();
    }
    int excl = s[t] - ts + bsum[blockIdx.x];
    if (base + 0 < N) rowptr[base + 0] = excl;
    if (base + 1 < N) rowptr[base + 1] = excl + v0;
    if (base + 2 < N) rowptr[base + 2] = excl + v0 + v1;
    if (base + 3 < N) rowptr[base + 3] = excl + v0 + v1 + v2;
}

__global__ __launch_bounds__(256) void k_fill(const int* __restrict__ src, const int* __restrict__ dst,
                                              const float* __restrict__ dinv, int* __restrict__ cursor,
                                              int* __restrict__ csr_src, float* __restrict__ csr_w, int E) {
    int e = blockIdx.x * 256 + threadIdx.x;
    if (e >= E) return;
    int s = src[e], d = dst[e];
    int pos = atomicAdd(&cursor[d], 1);
    csr_src[pos] = s;
    csr_w[pos] = dinv[s] * dinv[d];
}

// ---------------- GEMM: C_bf16[N,128] = bn(A)[N,128] @ W[128,128] ----------------
// IN_BF16: A is packed bf16 rows (uint2 = 4 features); scsh applied + ReLU.

template <int IN_BF16>
__global__ __launch_bounds__(256) void k_gemm(const void* __restrict__ Ain, const float* __restrict__ W,
                                              uint* __restrict__ C, int N, const float* __restrict__ scsh) {
    __shared__ float As[32][HD];
    __shared__ float Ws[HD][HD];
    const int t = threadIdx.x;
    const int row0 = blockIdx.x * 32;

    for (int i = t; i < HD * HD / 4; i += 256)
        ((float4*)Ws)[i] = ((const float4*)W)[i];
    for (int i = t; i < 32 * HD / 4; i += 256) {
        int r = i >> 5, q = i & 31;
        int gr = row0 + r;
        float4 v = make_float4(0.f, 0.f, 0.f, 0.f);
        if (gr < N) {
            if (IN_BF16) {
                uint2 ld = ((const uint2*)Ain)[(size_t)gr * 32 + q];
                v.x = bf_lo(ld.x); v.y = bf_hi(ld.x);
                v.z = bf_lo(ld.y); v.w = bf_hi(ld.y);
            } else {
                v = ((const float4*)Ain)[(size_t)gr * 32 + q];
            }
        }
        if (IN_BF16) {
            const float4 sc = ((const float4*)scsh)[q];
            const float4 sh = ((const float4*)scsh)[32 + q];
            v.x = fmaxf(fmaf(v.x, sc.x, sh.x), 0.f);
            v.y = fmaxf(fmaf(v.y, sc.y, sh.y), 0.f);
            v.z = fmaxf(fmaf(v.z, sc.z, sh.z), 0.f);
            v.w = fmaxf(fmaf(v.w, sc.w, sh.w), 0.f);
        }
        ((float4*)As)[i] = v;
    }
    __syncthreads();

    const int tx = t & 31, ty = t >> 5;
    const int c0 = tx * 4, r0 = ty * 4;
    float acc[4][4] = {};
#pragma unroll 8
    for (int k = 0; k < HD; ++k) {
        const float4 w = *(const float4*)&Ws[k][c0];
#pragma unroll
        for (int i = 0; i < 4; ++i) {
            const float a = As[r0 + i][k];
            acc[i][0] = fmaf(a, w.x, acc[i][0]);
            acc[i][1] = fmaf(a, w.y, acc[i][1]);
            acc[i][2] = fmaf(a, w.z, acc[i][2]);
            acc[i][3] = fmaf(a, w.w, acc[i][3]);
        }
    }
#pragma unroll
    for (int i = 0; i < 4; ++i) {
        int gr = row0 + r0 + i;
        if (gr < N) {
            uint2 p;
            p.x = pack_bf2(acc[i][0], acc[i][1]);
            p.y = pack_bf2(acc[i][2], acc[i][3]);
            *(uint2*)&C[(size_t)gr * 64 + (c0 >> 1)] = p;
        }
    }
}

// ---------------- fused aggregation: packed bf16 gather (4 rows/instr) + self + bias + BN stats ----
// wave layout: slot s = lane&15 (features 8s..8s+7, one uint4), quarter q = lane>>4 (edge j in group).
// virtual edge 0 = self-loop (w = dinv^2); virtual edges 1..deg = CSR edges.

#define GATHER_BLOCKS 2048

__global__ __launch_bounds__(256) void k_gather(const uint4* __restrict__ hW4, const int* __restrict__ rowptr,
                                                const int* __restrict__ rowend, const int* __restrict__ csr_src,
                                                const float* __restrict__ csr_w, const float* __restrict__ dinv,
                                                const float* __restrict__ bias, uint4* __restrict__ agg4,
                                                float* __restrict__ stats, int N) {
    const int l = threadIdx.x & 63;
    const int s = l & 15;
    const int q = l >> 4;
    const int wv = threadIdx.x >> 6;
    const int wid0 = blockIdx.x * 4 + wv;
    const int wstride = gridDim.x * 4;

    float bj[8];
    {
        const float4 b0 = ((const float4*)bias)[s * 2];
        const float4 b1 = ((const float4*)bias)[s * 2 + 1];
        bj[0] = b0.x; bj[1] = b0.y; bj[2] = b0.z; bj[3] = b0.w;
        bj[4] = b1.x; bj[5] = b1.y; bj[6] = b1.z; bj[7] = b1.w;
    }

    float ssum[8] = {0, 0, 0, 0, 0, 0, 0, 0};
    float ssq[8] = {0, 0, 0, 0, 0, 0, 0, 0};

    for (int n = wid0; n < N; n += wstride) {
        float sw = dinv[n];
        sw *= sw;
        const int rp = rowptr[n];
        const int re = rowend[n];
        const int deg1 = re - rp + 1;  // virtual edges: self + deg

        float a[8];
#pragma unroll
        for (int j = 0; j < 8; ++j) a[j] = (q == 0) ? bj[j] : 0.f;

        // prefetch first virtual edge for this lane
        int idx = n;
        float w = 0.f;
        {
            int vi = q;
            if (vi == 0) { w = sw; }
            else if (vi < deg1) { int ei = rp + vi - 1; idx = csr_src[ei]; w = csr_w[ei]; }
        }
        int base = 0;
        while (true) {
            uint4 r4 = hW4[idx * 16 + s];
            int base2 = base + 4;
            int idx2 = n;
            float w2 = 0.f;
            const bool more = base2 < deg1;
            if (more) {
                int vi = base2 + q;
                if (vi < deg1) { int ei = rp + vi - 1; idx2 = csr_src[ei]; w2 = csr_w[ei]; }
            }
            float f[8];
            unpack8(r4, f);
#pragma unroll
            for (int j = 0; j < 8; ++j) a[j] = fmaf(f[j], w, a[j]);
            if (!more) break;
            base = base2; idx = idx2; w = w2;
        }

        // cross-quarter reduce (4 partials per feature slot)
#pragma unroll
        for (int j = 0; j < 8; ++j) {
            float v = a[j];
            v += __shfl_xor(v, 16);
            v += __shfl_xor(v, 32);
            a[j] = v;
        }
        if (q == 0) {
            uint4 o;
            o.x = pack_bf2(a[0], a[1]);
            o.y = pack_bf2(a[2], a[3]);
            o.z = pack_bf2(a[4], a[5]);
            o.w = pack_bf2(a[6], a[7]);
            agg4[n * 16 + s] = o;
        }
#pragma unroll
        for (int j = 0; j < 8; ++j) {
            ssum[j] += a[j];
            ssq[j] = fmaf(a[j], a[j], ssq[j]);
        }
    }

    // block stats reduce: quarter-0 lanes hold (identical) totals
    __shared__ float red[2][4][16][8];
    if (q == 0) {
#pragma unroll
        for (int j = 0; j < 8; ++j) {
            red[0][wv][s][j] = ssum[j];
            red[1][wv][s][j] = ssq[j];
        }
    }
    __syncthreads();
    const int t = threadIdx.x;
    const int f = t & 127, half = t >> 7;
    float v = red[half][0][f >> 3][f & 7] + red[half][1][f >> 3][f & 7] +
              red[half][2][f >> 3][f & 7] + red[half][3][f >> 3][f & 7];
    unsafeAtomicAdd(&stats[half * HD + f], v);
}

// ---------------- BN finalize ----------------

__global__ __launch_bounds__(128) void k_bn_fin(const float* __restrict__ stats, const float* __restrict__ g,
                                                const float* __restrict__ be, float* __restrict__ scsh,
                                                float invN) {
    int f = threadIdx.x;
    float mean = stats[f] * invN;
    float var = fmaf(-mean, mean, stats[HD + f] * invN);
    float sc = g[f] * rsqrtf(var + BN_EPS);
    scsh[f] = sc;
    scsh[HD + f] = fmaf(-mean, sc, be[f]);
}

// ---------------- decode: 2 queries per wave, 4 rows per load instruction ----------------
// lane: h = l>>5 (query of pair), r = (l>>4)&1 (u or v), s = l&15 (feature slot)

__global__ __launch_bounds__(256) void k_decode(const uint4* __restrict__ h4, const float* __restrict__ scsh,
                                                const int* __restrict__ qu, const int* __restrict__ qv,
                                                float* __restrict__ out, int Q) {
    int tid = blockIdx.x * 256 + threadIdx.x;
    int wid = tid >> 6;
    int l = threadIdx.x & 63;
    int h = l >> 5, r = (l >> 4) & 1, s = l & 15;
    int qi = wid * 2 + h;
    if (qi >= Q) return;
    int node = r ? qv[qi] : qu[qi];
    uint4 row = h4[(size_t)node * 16 + s];

    float sc[8], sh[8];
    {
        const float4 c0 = ((const float4*)scsh)[s * 2];
        const float4 c1 = ((const float4*)scsh)[s * 2 + 1];
        const float4 h0 = ((const float4*)(scsh + HD))[s * 2];
        const float4 h1 = ((const float4*)(scsh + HD))[s * 2 + 1];
        sc[0] = c0.x; sc[1] = c0.y; sc[2] = c0.z; sc[3] = c0.w;
        sc[4] = c1.x; sc[5] = c1.y; sc[6] = c1.z; sc[7] = c1.w;
        sh[0] = h0.x; sh[1] = h0.y; sh[2] = h0.z; sh[3] = h0.w;
        sh[4] = h1.x; sh[5] = h1.y; sh[6] = h1.z; sh[7] = h1.w;
    }

    float own[8], oth[8];
    unpack8(row, own);
    uint4 p;
    p.x = __shfl_xor((int)row.x, 16);
    p.y = __shfl_xor((int)row.y, 16);
    p.z = __shfl_xor((int)row.z, 16);
    p.w = __shfl_xor((int)row.w, 16);
    unpack8(p, oth);

    float dot = 0.f;
#pragma unroll
    for (int j = 0; j < 8; ++j) {
        float a = fmaf(own[j], sc[j], sh[j]);
        float b = fmaf(oth[j], sc[j], sh[j]);
        dot = fmaf(a, b, dot);
    }
    dot += __shfl_xor(dot, 1);
    dot += __shfl_xor(dot, 2);
    dot += __shfl_xor(dot, 4);
    dot += __shfl_xor(dot, 8);
    if ((l & 31) == 0) out[qi] = dot;
}

// ---------------- launch ----------------

static inline size_t alignup(size_t x) { return (x + 511) & ~(size_t)511; }

extern "C" void kernel_launch(void* const* d_in, const int* in_sizes, int n_in,
                              void* d_out, int out_size, void* d_ws, size_t ws_size,
                              hipStream_t stream) {
    const float* x     = (const float*)d_in[0];
    const float* Wl[3]  = {(const float*)d_in[1], (const float*)d_in[5], (const float*)d_in[9]};
    const float* bl[3]  = {(const float*)d_in[2], (const float*)d_in[6], (const float*)d_in[10]};
    const float* gl[3]  = {(const float*)d_in[3], (const float*)d_in[7], (const float*)d_in[11]};
    const float* bel[3] = {(const float*)d_in[4], (const float*)d_in[8], (const float*)d_in[12]};
    const int* ei  = (const int*)d_in[13];
    const int* eli = (const int*)d_in[14];

    const int N = in_sizes[0] / HD;
    const int E = in_sizes[13] / 2;
    const int Q = in_sizes[14] / 2;
    const int* src = ei;
    const int* dst = ei + E;
    const int* qu = eli;
    const int* qv = eli + Q;
    float* out = (float*)d_out;

    char* ws = (char*)d_ws;
    size_t off = 0;
    float* dinv    = (float*)(ws + off); off = alignup(off + (size_t)N * 4);
    int*   cnt     = (int*)(ws + off);   off = alignup(off + (size_t)N * 4);
    int*   rowptr  = (int*)(ws + off);   off = alignup(off + (size_t)N * 4);
    int*   cursor  = (int*)(ws + off);   off = alignup(off + (size_t)N * 4);
    int*   bsum    = (int*)(ws + off);   off = alignup(off + 1024 * 4);
    float* stats   = (float*)(ws + off); off = alignup(off + 256 * 4);
    float* scsh0   = (float*)(ws + off); off = alignup(off + 256 * 4);
    float* scsh1   = (float*)(ws + off); off = alignup(off + 256 * 4);
    float* scsh2   = (float*)(ws + off); off = alignup(off + 256 * 4);
    int*   csr_src = (int*)(ws + off);   off = alignup(off + (size_t)E * 4);
    float* csr_w   = (float*)(ws + off); off = alignup(off + (size_t)E * 4);
    uint*  hB      = (uint*)(ws + off);  off = alignup(off + (size_t)N * HD * 2);  // bf16 gemm out
    uint*  hA      = (uint*)(ws + off);  off = alignup(off + (size_t)N * HD * 2);  // bf16 agg out
    (void)ws_size; (void)n_in; (void)out_size;

    float* scshl[3] = {scsh0, scsh1, scsh2};
    const float invN = 1.0f / (float)N;
    const int NB = (N + 1023) / 1024;
    const int eg = (E + 255) / 256;

    // ---- CSR build ----
    hipMemsetAsync(cnt, 0, (size_t)N * 4, stream);
    k_count<<<eg, 256, 0, stream>>>(dst, cnt, E);
    k_dinv<<<(N + 255) / 256, 256, 0, stream>>>(cnt, dinv, N);
    k_scan_a<<<NB, 256, 0, stream>>>(cnt, bsum, N);
    k_scan_b<<<1, 64, 0, stream>>>(bsum, NB);
    k_scan_c<<<NB, 256, 0, stream>>>(cnt, bsum, rowptr, N);
    hipMemcpyAsync(cursor, rowptr, (size_t)N * 4, hipMemcpyDeviceToDevice, stream);
    k_fill<<<eg, 256, 0, stream>>>(src, dst, dinv, cursor, csr_src, csr_w, E);

    // ---- 3 GCN layers ----
    for (int l = 0; l < 3; ++l) {
        if (l == 0)
            k_gemm<0><<<(N + 31) / 32, 256, 0, stream>>>(x, Wl[0], hB, N, nullptr);
        else
            k_gemm<1><<<(N + 31) / 32, 256, 0, stream>>>(hA, Wl[l], hB, N, scshl[l - 1]);
        hipMemsetAsync(stats, 0, 256 * 4, stream);
        k_gather<<<GATHER_BLOCKS, 256, 0, stream>>>((const uint4*)hB, rowptr, cursor, csr_src, csr_w,
                                                    dinv, bl[l], (uint4*)hA, stats, N);
        k_bn_fin<<<1, HD, 0, stream>>>(stats, gl[l], bel[l], scshl[l], invN);
    }

    const int dw = (Q + 1) / 2;  // decode waves (2 queries each)
    k_decode<<<(dw + 3) / 4, 256, 0, stream>>>((const uint4*)hA, scsh2, qu, qv, out, Q);
}

// Round 6
// 451.665 us; speedup vs baseline: 3.4493x; 1.2784x over previous
//
#include <hip/hip_runtime.h>

#define HD 128
#define BN_EPS 1e-5f

typedef unsigned int uint;
typedef unsigned short ushort;
typedef __attribute__((ext_vector_type(8))) short short8;
typedef __attribute__((ext_vector_type(4))) float f32x4;

union U4S8 { uint4 u; short8 s; };

// bf16x2 packed in a uint: lo half = even feature, hi half = odd feature
__device__ __forceinline__ float bf_lo(uint u) { return __uint_as_float(u << 16); }
__device__ __forceinline__ float bf_hi(uint u) { return __uint_as_float(u & 0xffff0000u); }
__device__ __forceinline__ uint bf_round(float f) {  // RNE to bf16 bits (in high 16)
    uint u = __float_as_uint(f);
    return (u + 0x7fffu + ((u >> 16) & 1u)) & 0xffff0000u;
}
__device__ __forceinline__ uint pack_bf2(float a, float b) {
    return (bf_round(a) >> 16) | bf_round(b);
}
__device__ __forceinline__ void unpack8(uint4 u, float* f) {
    f[0] = bf_lo(u.x); f[1] = bf_hi(u.x);
    f[2] = bf_lo(u.y); f[3] = bf_hi(u.y);
    f[4] = bf_lo(u.z); f[5] = bf_hi(u.z);
    f[6] = bf_lo(u.w); f[7] = bf_hi(u.w);
}

// ---------------- CSR build: count / dinv / scan / fill ----------------

__global__ __launch_bounds__(256) void k_count(const int* __restrict__ dst, int* __restrict__ cnt, int E) {
    int e = blockIdx.x * 256 + threadIdx.x;
    if (e < E) atomicAdd(&cnt[dst[e]], 1);
}

__global__ __launch_bounds__(256) void k_dinv(const int* __restrict__ cnt, float* __restrict__ dinv, int N) {
    int n = blockIdx.x * 256 + threadIdx.x;
    if (n < N) dinv[n] = rsqrtf((float)cnt[n] + 1.0f);
}

__global__ __launch_bounds__(256) void k_scan_a(const int* __restrict__ cnt, int* __restrict__ bsum, int N) {
    __shared__ int s[256];
    int base = blockIdx.x * 1024 + threadIdx.x * 4;
    int v = 0;
#pragma unroll
    for (int j = 0; j < 4; ++j) {
        int idx = base + j;
        if (idx < N) v += cnt[idx];
    }
    s[threadIdx.x] = v;
    __syncthreads();
    for (int o = 128; o; o >>= 1) {
        if (threadIdx.x < (unsigned)o) s[threadIdx.x] += s[threadIdx.x + o];
        __syncthreads();
    }
    if (threadIdx.x == 0) bsum[blockIdx.x] = s[0];
}

__global__ void k_scan_b(int* __restrict__ bsum, int NB) {
    if (threadIdx.x == 0 && blockIdx.x == 0) {
        int acc = 0;
        for (int i = 0; i < NB; ++i) {
            int v = bsum[i];
            bsum[i] = acc;
            acc += v;
        }
    }
}

__global__ __launch_bounds__(256) void k_scan_c(const int* __restrict__ cnt, const int* __restrict__ bsum,
                                                int* __restrict__ rowptr, int N) {
    __shared__ int s[256];
    const int t = threadIdx.x;
    int base = blockIdx.x * 1024 + t * 4;
    int v0 = 0, v1 = 0, v2 = 0, v3 = 0;
    if (base + 0 < N) v0 = cnt[base + 0];
    if (base + 1 < N) v1 = cnt[base + 1];
    if (base + 2 < N) v2 = cnt[base + 2];
    if (base + 3 < N) v3 = cnt[base + 3];
    int ts = v0 + v1 + v2 + v3;
    s[t] = ts;
    __syncthreads();
    for (int o = 1; o < 256; o <<= 1) {
        int add = (t >= o) ? s[t - o] : 0;
        __syncthreads();
        s[t] += add;
        __syncthreads();
    }
    int excl = s[t] - ts + bsum[blockIdx.x];
    if (base + 0 < N) rowptr[base + 0] = excl;
    if (base + 1 < N) rowptr[base + 1] = excl + v0;
    if (base + 2 < N) rowptr[base + 2] = excl + v0 + v1;
    if (base + 3 < N) rowptr[base + 3] = excl + v0 + v1 + v2;
}

__global__ __launch_bounds__(256) void k_fill(const int* __restrict__ src, const int* __restrict__ dst,
                                              const float* __restrict__ dinv, int* __restrict__ cursor,
                                              int* __restrict__ csr_src, float* __restrict__ csr_w, int E) {
    int e = blockIdx.x * 256 + threadIdx.x;
    if (e >= E) return;
    int s = src[e], d = dst[e];
    int pos = atomicAdd(&cursor[d], 1);
    csr_src[pos] = s;
    csr_w[pos] = dinv[s] * dinv[d];
}

// ---------------- W prep: wb[col][k] = bf16(W[k][col]) (transposed, packed rows) ----------------

__global__ __launch_bounds__(256) void k_wprep(const float* __restrict__ W, ushort* __restrict__ wb) {
    int t = blockIdx.x * 256 + threadIdx.x;  // 16384 = 128*128
    int k = t >> 7, col = t & 127;
    wb[col * 128 + k] = (ushort)(bf_round(W[t]) >> 16);
}

// ---------------- MFMA GEMM: C_bf16[N,128] = bn_relu(A)[N,128] @ W ----------------
// block = 4 waves, each wave 32 rows x 128 cols; K=128 in 4 steps of 32.
// A frag: lane(l) row = l&15, k = kk*32 + (l>>4)*8 + j  -> one uint4 from packed bf16 row.
// B frag: col = c*16 + (l&15), same k -> uint4 from LDS-staged transposed W (XOR-swizzled).
// D: col = l&15, row = (l>>4)*4 + reg.

template <int IN_BF16>
__global__ __launch_bounds__(256) void k_mm(const void* __restrict__ Ain, const uint4* __restrict__ wb4,
                                            uint* __restrict__ C, int N, const float* __restrict__ scsh) {
    __shared__ uint4 wl[2048];  // 32KB: idx = col*16 + kk*4 + g, stored at idx ^ ((idx>>4)&7)
    const int t = threadIdx.x;
#pragma unroll
    for (int i = 0; i < 8; ++i) {
        int idx = i * 256 + t;
        wl[idx ^ ((idx >> 4) & 7)] = wb4[idx];
    }
    __syncthreads();

    const int l = t & 63;
    const int w = t >> 6;
    const int r = l & 15;
    const int g = l >> 4;
    const int rbase = blockIdx.x * 128 + w * 32;

    short8 a[2][4];
#pragma unroll
    for (int tt = 0; tt < 2; ++tt) {
        int row = rbase + tt * 16 + r;
        bool ok = row < N;
#pragma unroll
        for (int kk = 0; kk < 4; ++kk) {
            U4S8 v;
            v.u = make_uint4(0u, 0u, 0u, 0u);
            if (ok) {
                if (IN_BF16) {
                    uint4 ld = ((const uint4*)Ain)[(size_t)row * 16 + kk * 4 + g];
                    float f[8];
                    unpack8(ld, f);
                    const float4 sc0 = ((const float4*)scsh)[kk * 8 + g * 2];
                    const float4 sc1 = ((const float4*)scsh)[kk * 8 + g * 2 + 1];
                    const float4 sh0 = ((const float4*)(scsh + HD))[kk * 8 + g * 2];
                    const float4 sh1 = ((const float4*)(scsh + HD))[kk * 8 + g * 2 + 1];
                    f[0] = fmaxf(fmaf(f[0], sc0.x, sh0.x), 0.f);
                    f[1] = fmaxf(fmaf(f[1], sc0.y, sh0.y), 0.f);
                    f[2] = fmaxf(fmaf(f[2], sc0.z, sh0.z), 0.f);
                    f[3] = fmaxf(fmaf(f[3], sc0.w, sh0.w), 0.f);
                    f[4] = fmaxf(fmaf(f[4], sc1.x, sh1.x), 0.f);
                    f[5] = fmaxf(fmaf(f[5], sc1.y, sh1.y), 0.f);
                    f[6] = fmaxf(fmaf(f[6], sc1.z, sh1.z), 0.f);
                    f[7] = fmaxf(fmaf(f[7], sc1.w, sh1.w), 0.f);
                    v.u.x = pack_bf2(f[0], f[1]);
                    v.u.y = pack_bf2(f[2], f[3]);
                    v.u.z = pack_bf2(f[4], f[5]);
                    v.u.w = pack_bf2(f[6], f[7]);
                } else {
                    const float4* A4 = (const float4*)Ain;
                    float4 x0 = A4[(size_t)row * 32 + kk * 8 + g * 2];
                    float4 x1 = A4[(size_t)row * 32 + kk * 8 + g * 2 + 1];
                    v.u.x = pack_bf2(x0.x, x0.y);
                    v.u.y = pack_bf2(x0.z, x0.w);
                    v.u.z = pack_bf2(x1.x, x1.y);
                    v.u.w = pack_bf2(x1.z, x1.w);
                }
            }
            a[tt][kk] = v.s;
        }
    }

    f32x4 acc[2][8];
#pragma unroll
    for (int tt = 0; tt < 2; ++tt)
#pragma unroll
        for (int c = 0; c < 8; ++c) acc[tt][c] = (f32x4){0.f, 0.f, 0.f, 0.f};

#pragma unroll
    for (int c = 0; c < 8; ++c) {
#pragma unroll
        for (int kk = 0; kk < 4; ++kk) {
            int idx = (c * 16 + r) * 16 + kk * 4 + g;
            U4S8 b;
            b.u = wl[idx ^ ((idx >> 4) & 7)];
            acc[0][c] = __builtin_amdgcn_mfma_f32_16x16x32_bf16(a[0][kk], b.s, acc[0][c], 0, 0, 0);
            acc[1][c] = __builtin_amdgcn_mfma_f32_16x16x32_bf16(a[1][kk], b.s, acc[1][c], 0, 0, 0);
        }
    }

    // epilogue: pack col pairs via lane-xor, even lanes store one uint (2 cols)
#pragma unroll
    for (int tt = 0; tt < 2; ++tt) {
#pragma unroll
        for (int j = 0; j < 4; ++j) {
            int row = rbase + tt * 16 + g * 4 + j;
#pragma unroll
            for (int c = 0; c < 8; ++c) {
                float own = acc[tt][c][j];
                float nb = __shfl_xor(own, 1);
                if (row < N && !(l & 1)) C[(size_t)row * 64 + c * 8 + (r >> 1)] = pack_bf2(own, nb);
            }
        }
    }
}

// ---------------- fused aggregation: packed bf16 gather (4 rows/instr) + self + bias + BN stats ----
// wave layout: slot s = lane&15 (features 8s..8s+7, one uint4), quarter q = lane>>4 (edge j in group).
// virtual edge 0 = self-loop (w = dinv^2); virtual edges 1..deg = CSR edges.

#define GATHER_BLOCKS 2048

__global__ __launch_bounds__(256) void k_gather(const uint4* __restrict__ hW4, const int* __restrict__ rowptr,
                                                const int* __restrict__ rowend, const int* __restrict__ csr_src,
                                                const float* __restrict__ csr_w, const float* __restrict__ dinv,
                                                const float* __restrict__ bias, uint4* __restrict__ agg4,
                                                float* __restrict__ stats, int N) {
    const int l = threadIdx.x & 63;
    const int s = l & 15;
    const int q = l >> 4;
    const int wv = threadIdx.x >> 6;
    const int wid0 = blockIdx.x * 4 + wv;
    const int wstride = gridDim.x * 4;

    float bj[8];
    {
        const float4 b0 = ((const float4*)bias)[s * 2];
        const float4 b1 = ((const float4*)bias)[s * 2 + 1];
        bj[0] = b0.x; bj[1] = b0.y; bj[2] = b0.z; bj[3] = b0.w;
        bj[4] = b1.x; bj[5] = b1.y; bj[6] = b1.z; bj[7] = b1.w;
    }

    float ssum[8] = {0, 0, 0, 0, 0, 0, 0, 0};
    float ssq[8] = {0, 0, 0, 0, 0, 0, 0, 0};

    for (int n = wid0; n < N; n += wstride) {
        float sw = dinv[n];
        sw *= sw;
        const int rp = rowptr[n];
        const int re = rowend[n];
        const int deg1 = re - rp + 1;  // virtual edges: self + deg

        float a[8];
#pragma unroll
        for (int j = 0; j < 8; ++j) a[j] = (q == 0) ? bj[j] : 0.f;

        int idx = n;
        float w = 0.f;
        {
            int vi = q;
            if (vi == 0) { w = sw; }
            else if (vi < deg1) { int ei = rp + vi - 1; idx = csr_src[ei]; w = csr_w[ei]; }
        }
        int base = 0;
        while (true) {
            uint4 r4 = hW4[idx * 16 + s];
            int base2 = base + 4;
            int idx2 = n;
            float w2 = 0.f;
            const bool more = base2 < deg1;
            if (more) {
                int vi = base2 + q;
                if (vi < deg1) { int ei = rp + vi - 1; idx2 = csr_src[ei]; w2 = csr_w[ei]; }
            }
            float f[8];
            unpack8(r4, f);
#pragma unroll
            for (int j = 0; j < 8; ++j) a[j] = fmaf(f[j], w, a[j]);
            if (!more) break;
            base = base2; idx = idx2; w = w2;
        }

#pragma unroll
        for (int j = 0; j < 8; ++j) {
            float v = a[j];
            v += __shfl_xor(v, 16);
            v += __shfl_xor(v, 32);
            a[j] = v;
        }
        if (q == 0) {
            uint4 o;
            o.x = pack_bf2(a[0], a[1]);
            o.y = pack_bf2(a[2], a[3]);
            o.z = pack_bf2(a[4], a[5]);
            o.w = pack_bf2(a[6], a[7]);
            agg4[n * 16 + s] = o;
        }
#pragma unroll
        for (int j = 0; j < 8; ++j) {
            ssum[j] += a[j];
            ssq[j] = fmaf(a[j], a[j], ssq[j]);
        }
    }

    __shared__ float red[2][4][16][8];
    if (q == 0) {
#pragma unroll
        for (int j = 0; j < 8; ++j) {
            red[0][wv][s][j] = ssum[j];
            red[1][wv][s][j] = ssq[j];
        }
    }
    __syncthreads();
    const int t = threadIdx.x;
    const int f = t & 127, half = t >> 7;
    float v = red[half][0][f >> 3][f & 7] + red[half][1][f >> 3][f & 7] +
              red[half][2][f >> 3][f & 7] + red[half][3][f >> 3][f & 7];
    unsafeAtomicAdd(&stats[half * HD + f], v);
}

// ---------------- BN finalize ----------------

__global__ __launch_bounds__(128) void k_bn_fin(const float* __restrict__ stats, const float* __restrict__ g,
                                                const float* __restrict__ be, float* __restrict__ scsh,
                                                float invN) {
    int f = threadIdx.x;
    float mean = stats[f] * invN;
    float var = fmaf(-mean, mean, stats[HD + f] * invN);
    float sc = g[f] * rsqrtf(var + BN_EPS);
    scsh[f] = sc;
    scsh[HD + f] = fmaf(-mean, sc, be[f]);
}

// ---------------- decode: 2 queries per wave, 4 rows per load instruction ----------------

__global__ __launch_bounds__(256) void k_decode(const uint4* __restrict__ h4, const float* __restrict__ scsh,
                                                const int* __restrict__ qu, const int* __restrict__ qv,
                                                float* __restrict__ out, int Q) {
    int tid = blockIdx.x * 256 + threadIdx.x;
    int wid = tid >> 6;
    int l = threadIdx.x & 63;
    int h = l >> 5, r = (l >> 4) & 1, s = l & 15;
    int qi = wid * 2 + h;
    if (qi >= Q) return;
    int node = r ? qv[qi] : qu[qi];
    uint4 row = h4[(size_t)node * 16 + s];

    float sc[8], sh[8];
    {
        const float4 c0 = ((const float4*)scsh)[s * 2];
        const float4 c1 = ((const float4*)scsh)[s * 2 + 1];
        const float4 h0 = ((const float4*)(scsh + HD))[s * 2];
        const float4 h1 = ((const float4*)(scsh + HD))[s * 2 + 1];
        sc[0] = c0.x; sc[1] = c0.y; sc[2] = c0.z; sc[3] = c0.w;
        sc[4] = c1.x; sc[5] = c1.y; sc[6] = c1.z; sc[7] = c1.w;
        sh[0] = h0.x; sh[1] = h0.y; sh[2] = h0.z; sh[3] = h0.w;
        sh[4] = h1.x; sh[5] = h1.y; sh[6] = h1.z; sh[7] = h1.w;
    }

    float own[8], oth[8];
    unpack8(row, own);
    uint4 p;
    p.x = __shfl_xor((int)row.x, 16);
    p.y = __shfl_xor((int)row.y, 16);
    p.z = __shfl_xor((int)row.z, 16);
    p.w = __shfl_xor((int)row.w, 16);
    unpack8(p, oth);

    float dot = 0.f;
#pragma unroll
    for (int j = 0; j < 8; ++j) {
        float a = fmaf(own[j], sc[j], sh[j]);
        float b = fmaf(oth[j], sc[j], sh[j]);
        dot = fmaf(a, b, dot);
    }
    dot += __shfl_xor(dot, 1);
    dot += __shfl_xor(dot, 2);
    dot += __shfl_xor(dot, 4);
    dot += __shfl_xor(dot, 8);
    if ((l & 31) == 0) out[qi] = dot;
}

// ---------------- launch ----------------

static inline size_t alignup(size_t x) { return (x + 511) & ~(size_t)511; }

extern "C" void kernel_launch(void* const* d_in, const int* in_sizes, int n_in,
                              void* d_out, int out_size, void* d_ws, size_t ws_size,
                              hipStream_t stream) {
    const float* x     = (const float*)d_in[0];
    const float* Wl[3]  = {(const float*)d_in[1], (const float*)d_in[5], (const float*)d_in[9]};
    const float* bl[3]  = {(const float*)d_in[2], (const float*)d_in[6], (const float*)d_in[10]};
    const float* gl[3]  = {(const float*)d_in[3], (const float*)d_in[7], (const float*)d_in[11]};
    const float* bel[3] = {(const float*)d_in[4], (const float*)d_in[8], (const float*)d_in[12]};
    const int* ei  = (const int*)d_in[13];
    const int* eli = (const int*)d_in[14];

    const int N = in_sizes[0] / HD;
    const int E = in_sizes[13] / 2;
    const int Q = in_sizes[14] / 2;
    const int* src = ei;
    const int* dst = ei + E;
    const int* qu = eli;
    const int* qv = eli + Q;
    float* out = (float*)d_out;

    char* ws = (char*)d_ws;
    size_t off = 0;
    float* dinv    = (float*)(ws + off); off = alignup(off + (size_t)N * 4);
    int*   cnt     = (int*)(ws + off);   off = alignup(off + (size_t)N * 4);
    int*   rowptr  = (int*)(ws + off);   off = alignup(off + (size_t)N * 4);
    int*   cursor  = (int*)(ws + off);   off = alignup(off + (size_t)N * 4);
    int*   bsum    = (int*)(ws + off);   off = alignup(off + 1024 * 4);
    float* stats   = (float*)(ws + off); off = alignup(off + 256 * 4);
    float* scsh0   = (float*)(ws + off); off = alignup(off + 256 * 4);
    float* scsh1   = (float*)(ws + off); off = alignup(off + 256 * 4);
    float* scsh2   = (float*)(ws + off); off = alignup(off + 256 * 4);
    ushort* wb     = (ushort*)(ws + off); off = alignup(off + 128 * 128 * 2);
    int*   csr_src = (int*)(ws + off);   off = alignup(off + (size_t)E * 4);
    float* csr_w   = (float*)(ws + off); off = alignup(off + (size_t)E * 4);
    uint*  hB      = (uint*)(ws + off);  off = alignup(off + (size_t)N * HD * 2);  // bf16 gemm out
    uint*  hA      = (uint*)(ws + off);  off = alignup(off + (size_t)N * HD * 2);  // bf16 agg out
    (void)ws_size; (void)n_in; (void)out_size;

    float* scshl[3] = {scsh0, scsh1, scsh2};
    const float invN = 1.0f / (float)N;
    const int NB = (N + 1023) / 1024;
    const int eg = (E + 255) / 256;

    // ---- CSR build ----
    hipMemsetAsync(cnt, 0, (size_t)N * 4, stream);
    k_count<<<eg, 256, 0, stream>>>(dst, cnt, E);
    k_dinv<<<(N + 255) / 256, 256, 0, stream>>>(cnt, dinv, N);
    k_scan_a<<<NB, 256, 0, stream>>>(cnt, bsum, N);
    k_scan_b<<<1, 64, 0, stream>>>(bsum, NB);
    k_scan_c<<<NB, 256, 0, stream>>>(cnt, bsum, rowptr, N);
    hipMemcpyAsync(cursor, rowptr, (size_t)N * 4, hipMemcpyDeviceToDevice, stream);
    k_fill<<<eg, 256, 0, stream>>>(src, dst, dinv, cursor, csr_src, csr_w, E);

    // ---- 3 GCN layers ----
    const int mmg = (N + 127) / 128;
    for (int l = 0; l < 3; ++l) {
        k_wprep<<<64, 256, 0, stream>>>(Wl[l], wb);
        if (l == 0)
            k_mm<0><<<mmg, 256, 0, stream>>>(x, (const uint4*)wb, hB, N, nullptr);
        else
            k_mm<1><<<mmg, 256, 0, stream>>>(hA, (const uint4*)wb, hB, N, scshl[l - 1]);
        hipMemsetAsync(stats, 0, 256 * 4, stream);
        k_gather<<<GATHER_BLOCKS, 256, 0, stream>>>((const uint4*)hB, rowptr, cursor, csr_src, csr_w,
                                                    dinv, bl[l], (uint4*)hA, stats, N);
        k_bn_fin<<<1, HD, 0, stream>>>(stats, gl[l], bel[l], scshl[l], invN);
    }

    const int dw = (Q + 1) / 2;  // decode waves (2 queries each)
    k_decode<<<(dw + 3) / 4, 256, 0, stream>>>((const uint4*)hA, scsh2, qu, qv, out, Q);
}